// Round 4
// baseline (13216.910 us; speedup 1.0000x reference)
//
#include <hip/hip_runtime.h>
#include <hip/hip_bf16.h>
#include <cstdint>

#define TENC 100
#define TDEC 25
#define BATCH 512
#define DIN 96
#define HDIM 1024

// quaternion multiplication tables for qlinear:
// out_comp = sum_c sgn[comp][c] * x_c @ W[widx[comp][c]]
__device__ __constant__ int q_widx[4][4] = {{0,1,2,3},{1,0,3,2},{2,3,0,1},{3,2,1,0}};
__device__ __constant__ float q_sgn[4][4] = {{1.f,-1.f,-1.f,-1.f},
                                             {1.f, 1.f, 1.f,-1.f},
                                             {1.f,-1.f, 1.f, 1.f},
                                             {1.f, 1.f,-1.f, 1.f}};

// Build effective matrix M [4*nin x 4*nout] from W [4, nin, nout]:
// M[c*nin+m][comp*nout+o] = sgn[comp][c] * W[widx[comp][c]][m][o]
// (multiplication by +-1.0 is exact; negation commutes with IEEE rounding,
//  so sign-baked chains round identically to XLA's subtract-of-positive-dots)
__global__ void build_eff_kernel(const float* __restrict__ W, float* __restrict__ M,
                                 int nin, int nout) {
    int idx = blockIdx.x * blockDim.x + threadIdx.x;
    int ncol = nout * 4;
    int total = nin * 4 * ncol;
    if (idx >= total) return;
    int col = idx % ncol;
    int k = idx / ncol;
    int c = k / nin, m = k - c * nin;
    int comp = col / nout, o = col - comp * nout;
    M[idx] = q_sgn[comp][c] * W[(size_t)(q_widx[comp][c] * nin + m) * nout + o];
}

// XLA-CPU f32 tanh: Eigen-derived rational polynomial as emitted by XLA's
// elemental IR emitter (no FMA contraction - plain mul/add), with the tiny-x
// passthrough and the +-7.99881172180175781 clamp.
__device__ inline float xla_tanh(float x) {
    float ax = fabsf(x);
    if (ax < 0.0004f) return x;
    float t = fminf(fmaxf(x, -7.99881172180175781f), 7.99881172180175781f);
    float x2 = __fmul_rn(t, t);
    float p = -2.76076847742355e-16f;
    p = __fadd_rn(__fmul_rn(p, x2), 2.00018790482477e-13f);
    p = __fadd_rn(__fmul_rn(p, x2), -8.60467152213735e-11f);
    p = __fadd_rn(__fmul_rn(p, x2), 5.12229709037114e-08f);
    p = __fadd_rn(__fmul_rn(p, x2), 1.48572235717979e-05f);
    p = __fadd_rn(__fmul_rn(p, x2), 6.37261928875436e-04f);
    p = __fadd_rn(__fmul_rn(p, x2), 4.89352455891786e-03f);
    float num = __fmul_rn(t, p);
    float q = 1.19825839466702e-06f;
    q = __fadd_rn(__fmul_rn(q, x2), 1.18534705686654e-04f);
    q = __fadd_rn(__fmul_rn(q, x2), 2.26843463243900e-03f);
    q = __fadd_rn(__fmul_rn(q, x2), 4.89352518554385e-03f);
    return __fdiv_rn(num, q);
}

// XLA-replicating GEMM:
//   For each pass: out_pass = ((P0 + P1) + P2) + P3, where P_c is a SINGLE
//   ascending-k chain  acc = add(acc, mul(a,b))  (two roundings per k --
//   Eigen dot thunk in the AVX-only jaxlib wheel has no FMA) over K-block c,
//   matching the reference's left-to-right  xr@Wr - xi@Wi - xj@Wj - xk@Wk
//   (signs baked).  rs = (pass0 + bias); rs = rs + pass1; optional XLA tanh.
// Tile 64x64, 256 threads, 4x4 micro.
template<bool TANH, bool HAS2>
__global__ __launch_bounds__(256)
void gemm_xla(const float* __restrict__ A1, int lda1, int nin1, const float* __restrict__ B1,
              const float* __restrict__ A2, int lda2, int nin2, const float* __restrict__ B2,
              int N, const float* __restrict__ bias, float* __restrict__ C) {
    __shared__ __align__(16) float As[64][68];   // [k][row]
    __shared__ __align__(16) float Bs[64][64];   // [k][col]

    const int tid = threadIdx.x;
    const int tx = tid & 15, ty = tid >> 4;      // col micro, row micro
    const int r0 = blockIdx.y * 64;
    const int c0 = blockIdx.x * 64;
    const int lk = tid & 63, lr = tid >> 6;      // loader coords

    float rs[4][4];   // running result across passes
    float cb[4][4];   // per-pass combined (chain of block partials)
    float a4[4][4];   // current block's mul/add chain

    #pragma unroll
    for (int i = 0; i < 4; ++i)
        #pragma unroll
        for (int j = 0; j < 4; ++j) rs[i][j] = 0.f;

    const int npass = HAS2 ? 2 : 1;
    for (int pass = 0; pass < npass; ++pass) {
        const float* A = pass ? A2 : A1;
        const float* B = pass ? B2 : B1;
        const int lda = pass ? lda2 : lda1;
        const int nin = pass ? nin2 : nin1;

        #pragma unroll
        for (int i = 0; i < 4; ++i)
            #pragma unroll
            for (int j = 0; j < 4; ++j) cb[i][j] = 0.f;

        for (int c = 0; c < 4; ++c) {
            #pragma unroll
            for (int i = 0; i < 4; ++i)
                #pragma unroll
                for (int j = 0; j < 4; ++j) a4[i][j] = 0.f;

            for (int kb = 0; kb < nin; kb += 64) {
                const int kw = (nin - kb < 64) ? (nin - kb) : 64;
                const int k0 = c * nin + kb;
                __syncthreads();
                if (lk < kw) {                    // A tile: k-fast, coalesced on k
                    const float* ap = A + (size_t)(r0 + lr) * lda + (k0 + lk);
                    #pragma unroll
                    for (int i = 0; i < 16; ++i)
                        As[lk][lr + 4 * i] = ap[(size_t)(4 * i) * lda];
                }
                {                                 // B tile: col-fast, coalesced
                    const int ccol = c0 + lk;
                    #pragma unroll
                    for (int i = 0; i < 16; ++i) {
                        int k = lr + 4 * i;
                        if (k < kw)
                            Bs[k][lk] = (ccol < N) ? B[(size_t)(k0 + k) * N + ccol] : 0.f;
                    }
                }
                __syncthreads();
                #pragma unroll 4
                for (int k = 0; k < kw; ++k) {
                    float4 av = *reinterpret_cast<const float4*>(&As[k][ty * 4]);
                    float4 bv = *reinterpret_cast<const float4*>(&Bs[k][tx * 4]);
                    float aa[4] = {av.x, av.y, av.z, av.w};
                    float bb[4] = {bv.x, bv.y, bv.z, bv.w};
                    #pragma unroll
                    for (int i = 0; i < 4; ++i)
                        #pragma unroll
                        for (int j = 0; j < 4; ++j)
                            a4[i][j] = __fadd_rn(a4[i][j], __fmul_rn(aa[i], bb[j]));
                }
            }
            #pragma unroll
            for (int i = 0; i < 4; ++i)
                #pragma unroll
                for (int j = 0; j < 4; ++j)
                    cb[i][j] = __fadd_rn(cb[i][j], a4[i][j]);
        }

        if (pass == 0) {
            const int ccol = c0 + tx * 4;
            float b4[4] = {0.f, 0.f, 0.f, 0.f};
            if (bias != nullptr && ccol < N) {
                float4 bb4 = *reinterpret_cast<const float4*>(bias + ccol);
                b4[0] = bb4.x; b4[1] = bb4.y; b4[2] = bb4.z; b4[3] = bb4.w;
            }
            #pragma unroll
            for (int i = 0; i < 4; ++i)
                #pragma unroll
                for (int j = 0; j < 4; ++j)
                    rs[i][j] = (bias != nullptr) ? __fadd_rn(cb[i][j], b4[j]) : cb[i][j];
        } else {
            #pragma unroll
            for (int i = 0; i < 4; ++i)
                #pragma unroll
                for (int j = 0; j < 4; ++j)
                    rs[i][j] = __fadd_rn(rs[i][j], cb[i][j]);
        }
    }

    const int ccol = c0 + tx * 4;
    if (ccol < N) {
        #pragma unroll
        for (int i = 0; i < 4; ++i) {
            int r = r0 + ty * 4 + i;
            float o[4];
            #pragma unroll
            for (int j = 0; j < 4; ++j) {
                float v = rs[i][j];
                if (TANH) v = xla_tanh(v);
                o[j] = v;
            }
            *reinterpret_cast<float4*>(C + (size_t)r * N + ccol) =
                make_float4(o[0], o[1], o[2], o[3]);
        }
    }
}

// XLA-order per-quaternion normalize + Hamilton product.
// Every product individually rounded (no contraction), sums left-to-right,
// IEEE sqrt/div - matching the emitted elementwise HLO exactly.
__global__ void qmul_norm_kernel(const float* __restrict__ pred,
                                 const float* __restrict__ pre,
                                 float* __restrict__ out, int nq) {
    int q = blockIdx.x * blockDim.x + threadIdx.x;
    if (q >= nq) return;
    int b = q / 24, n = q - b * 24;
    const float* p = pred + (size_t)b * 96 + n;
    float pw = p[0], px = p[24], py = p[48], pz = p[72];
    float s = __fadd_rn(__fadd_rn(__fadd_rn(__fmul_rn(pw, pw), __fmul_rn(px, px)),
                                  __fmul_rn(py, py)), __fmul_rn(pz, pz));
    float nr = sqrtf(s);
    float nm = fmaxf(nr, 1e-12f);
    pw = __fdiv_rn(pw, nm); px = __fdiv_rn(px, nm);
    py = __fdiv_rn(py, nm); pz = __fdiv_rn(pz, nm);
    const float* r = pre + (size_t)b * 96 + n;
    float rw = r[0], rx = r[24], ry = r[48], rz = r[72];
    float* o = out + (size_t)b * 96 + n;
    // comp0: ((w*rw - x*rx) - y*ry) - z*rz
    o[0]  = __fsub_rn(__fsub_rn(__fsub_rn(__fmul_rn(pw, rw), __fmul_rn(px, rx)),
                                __fmul_rn(py, ry)), __fmul_rn(pz, rz));
    // comp1: ((w*rx + x*rw) + y*rz) - z*ry
    o[24] = __fsub_rn(__fadd_rn(__fadd_rn(__fmul_rn(pw, rx), __fmul_rn(px, rw)),
                                __fmul_rn(py, rz)), __fmul_rn(pz, ry));
    // comp2: ((w*ry - x*rz) + y*rw) + z*rx
    o[48] = __fadd_rn(__fadd_rn(__fsub_rn(__fmul_rn(pw, ry), __fmul_rn(px, rz)),
                                __fmul_rn(py, rw)), __fmul_rn(pz, rx));
    // comp3: ((w*rz + x*ry) - y*rx) + z*rw
    o[72] = __fadd_rn(__fsub_rn(__fadd_rn(__fmul_rn(pw, rz), __fmul_rn(px, ry)),
                                __fmul_rn(py, rx)), __fmul_rn(pz, rw));
}

extern "C" void kernel_launch(void* const* d_in, const int* in_sizes, int n_in,
                              void* d_out, int out_size, void* d_ws, size_t ws_size,
                              hipStream_t stream) {
    const float* inp    = (const float*)d_in[0];  // [100,512,96]
    const float* target = (const float*)d_in[1];  // [26,512,96]
    const float* Wx     = (const float*)d_in[2];  // [4,24,256]
    const float* bx     = (const float*)d_in[3];  // [1024]
    const float* Wh     = (const float*)d_in[4];  // [4,256,256]
    const float* Wl     = (const float*)d_in[5];  // [4,256,24]
    const float* bl     = (const float*)d_in[6];  // [96]

    float* out = (float*)d_out;
    float* out_enc = out;                                   // [100,512,96]
    float* out_dec = out + (size_t)TENC * BATCH * DIN;      // [25,512,96]

    size_t off = 0;
    auto alloc = [&](size_t nf) -> float* {
        float* p = (float*)((char*)d_ws + off);
        off += nf * sizeof(float);
        return p;
    };
    float* M_x = alloc((size_t)DIN * HDIM);    // 96 x 1024
    float* M_h = alloc((size_t)HDIM * HDIM);   // 1024 x 1024
    float* M_l = alloc((size_t)HDIM * DIN);    // 1024 x 96
    float* hb0 = alloc((size_t)BATCH * HDIM);
    float* hb1 = alloc((size_t)BATCH * HDIM);

    const size_t SH = (size_t)BATCH * HDIM;    // 524288
    const size_t SX = (size_t)BATCH * DIN;     // 49152
    size_t need_hs = (size_t)(TENC + 1) * SH + (size_t)TENC * SX;
    bool use_hs = (off + need_hs * sizeof(float) <= ws_size);
    float* hs = nullptr;
    float* ptmp = nullptr;
    if (use_hs) {
        hs = alloc((size_t)(TENC + 1) * SH);
        ptmp = alloc((size_t)TENC * SX);
    } else {
        ptmp = alloc(SX);
    }

    // ---- build effective matrices ----
    {
        int t1 = 4 * 24 * 4 * 256;
        build_eff_kernel<<<(t1 + 255) / 256, 256, 0, stream>>>(Wx, M_x, 24, 256);
        int t2 = 4 * 256 * 4 * 256;
        build_eff_kernel<<<(t2 + 255) / 256, 256, 0, stream>>>(Wh, M_h, 256, 256);
        int t3 = 4 * 256 * 4 * 24;
        build_eff_kernel<<<(t3 + 255) / 256, 256, 0, stream>>>(Wl, M_l, 256, 24);
    }

    dim3 gRnn(HDIM / 64, BATCH / 64);            // (16, 8)
    dim3 gPredDec((DIN + 63) / 64, BATCH / 64);  // (2, 8)

    float* h_prev = nullptr;

    if (use_hs) {
        hipMemsetAsync(hs, 0, SH * sizeof(float), stream);  // h0 = 0
        for (int t = 0; t < TENC; ++t) {
            gemm_xla<true, true><<<gRnn, 256, 0, stream>>>(
                inp + (size_t)t * SX, DIN, DIN / 4, M_x,
                hs + (size_t)t * SH, HDIM, HDIM / 4, M_h,
                HDIM, bx, hs + (size_t)(t + 1) * SH);
        }
        dim3 gPredEnc((DIN + 63) / 64, (TENC * BATCH) / 64);  // (2, 800)
        gemm_xla<false, false><<<gPredEnc, 256, 0, stream>>>(
            hs + SH, HDIM, HDIM / 4, M_l,
            nullptr, 0, 0, nullptr,
            DIN, bl, ptmp);
        int nq = TENC * BATCH * 24;
        qmul_norm_kernel<<<(nq + 255) / 256, 256, 0, stream>>>(ptmp, inp, out_enc, nq);
        h_prev = hs + (size_t)TENC * SH;
    } else {
        hipMemsetAsync(hb0, 0, SH * sizeof(float), stream);  // h0 = 0
        float* hin = hb0;
        float* hout = hb1;
        for (int t = 0; t < TENC; ++t) {
            gemm_xla<true, true><<<gRnn, 256, 0, stream>>>(
                inp + (size_t)t * SX, DIN, DIN / 4, M_x,
                hin, HDIM, HDIM / 4, M_h,
                HDIM, bx, hout);
            gemm_xla<false, false><<<gPredDec, 256, 0, stream>>>(
                hout, HDIM, HDIM / 4, M_l, nullptr, 0, 0, nullptr,
                DIN, bl, ptmp);
            int nq = BATCH * 24;
            qmul_norm_kernel<<<(nq + 255) / 256, 256, 0, stream>>>(
                ptmp, inp + (size_t)t * SX, out_enc + (size_t)t * SX, nq);
            float* tmp = hin; hin = hout; hout = tmp;
        }
        h_prev = hin;
    }

    // ---- decoder ----
    const float* x = target;  // target[0]
    float* hin = h_prev;
    int cur = (hin == hb0) ? 1 : 0;  // never write the buffer we're reading
    for (int t = 0; t < TDEC; ++t) {
        float* hout = cur ? hb1 : hb0;
        gemm_xla<true, true><<<gRnn, 256, 0, stream>>>(
            x, DIN, DIN / 4, M_x,
            hin, HDIM, HDIM / 4, M_h,
            HDIM, bx, hout);
        gemm_xla<false, false><<<gPredDec, 256, 0, stream>>>(
            hout, HDIM, HDIM / 4, M_l, nullptr, 0, 0, nullptr,
            DIN, bl, ptmp);
        int nq = BATCH * 24;
        qmul_norm_kernel<<<(nq + 255) / 256, 256, 0, stream>>>(
            ptmp, x, out_dec + (size_t)t * SX, nq);
        x = out_dec + (size_t)t * SX;
        hin = hout;
        cur ^= 1;
    }
}